// Round 1
// baseline (104.555 us; speedup 1.0000x reference)
//
#include <hip/hip_runtime.h>
#include <math.h>

#define B_TOT 16384
#define H     128
#define NC    10
#define NATT  3
#define TR    16      // rows per block; 4 waves split the 128 cols (32 each)
#define HBS   136     // bf16 LDS row stride in ushorts (272B, 16B-aligned)
#define KT    5       // degree-4 minimax of exp on [-1,1]; max err ~5.9e-4
#define EPS   1e-5f

typedef __attribute__((ext_vector_type(8))) short bf16x8;
typedef __attribute__((ext_vector_type(4))) float f32x4;

__device__ __forceinline__ ushort f2bf(float f) {
    union { float f; unsigned u; } v; v.f = f;
    unsigned r = v.u + 0x7fffu + ((v.u >> 16) & 1u);   // RNE
    return (ushort)(r >> 16);
}

// tanh(a) = 1 - 2/(e^{2a}+1); saturates correctly for |a| large (inf -> 1, 0 -> -1)
__device__ __forceinline__ float fast_tanh(float a) {
    float t = __expf(2.f * a);
    return 1.f - 2.f * __builtin_amdgcn_rcpf(t + 1.f);
}

template<int CTRL>
__device__ __forceinline__ float dpp_add(float v) {
    int x = __float_as_int(v);
    int y = __builtin_amdgcn_update_dpp(0, x, CTRL, 0xf, 0xf, false);
    return v + __int_as_float(y);
}
// all-reduce over the 16 lanes of a DPP row (lanes differing in s)
__device__ __forceinline__ float red16(float v) {
    v = dpp_add<0x121>(v);   // row_ror:1
    v = dpp_add<0x122>(v);   // row_ror:2
    v = dpp_add<0x124>(v);   // row_ror:4
    v = dpp_add<0x128>(v);   // row_ror:8
    return v;
}

// ---- prep: wt[mat][n][k]; mat0=W_in^T, mat1..3=W_att^T, mat4=W_c^T padded to 16 rows ----
extern "C" __global__ __launch_bounds__(256)
void prep_weights(const float* __restrict__ W_in,
                  const float* __restrict__ W_att,
                  const float* __restrict__ W_c,
                  ushort* __restrict__ wt)
{
    int i = blockIdx.x * 256 + threadIdx.x;
    if (i < 65536) {
        int mat = i >> 14, idx = i & 16383;
        int k = idx >> 7, n = idx & 127;
        float v = (mat == 0) ? W_in[idx] : W_att[(mat - 1) * 16384 + idx];
        wt[mat * 16384 + n * H + k] = f2bf(v);
    } else if (i < 65536 + 2048) {
        int idx = i - 65536;
        int n = idx >> 7, k = idx & 127;
        float v = (n < NC) ? W_c[k * NC + n] : 0.f;
        wt[65536 + n * H + k] = f2bf(v);
    }
}

extern "C" __global__ __launch_bounds__(256, 4)
void simple_attention_kernel(const float* __restrict__ x,
                             const float* __restrict__ b_in,
                             const float* __restrict__ b_att,
                             const float* __restrict__ gamma,
                             const float* __restrict__ beta,
                             const float* __restrict__ b_c,
                             const ushort* __restrict__ wt,
                             float* __restrict__ out)
{
    __shared__ __align__(16) ushort ab[TR * HBS];     // bf16 A-tile (shared by 4 waves)
    __shared__ __align__(16) float  exm[4 * 16 * 12]; // moment exchange: 9 vals/row, stride 12
    __shared__ __align__(16) float  exl[4 * 16 * 2];  // LN exchange

    const int tid  = threadIdx.x;
    const int wv   = tid >> 6;          // wave 0..3 owns cols [32wv, 32wv+32)
    const int lane = tid & 63;
    const int s    = lane & 15;
    const int q    = lane >> 4;
    const size_t rowBase = (size_t)blockIdx.x * TR;

    float h[2][4];     // h[t][r]: row 4q+r, col 32wv+16t+s
    f32x4 acc[2];

    // ---- stage x tile to LDS as bf16: wave wv converts k-slice [32wv, 32wv+32) ----
    {
        const float* xp = x + (rowBase + s) * H + 32 * wv + q * 8;
        float4 v0 = *(const float4*)xp;
        float4 v1 = *(const float4*)(xp + 4);
        bf16x8 a;
        a[0] = f2bf(v0.x); a[1] = f2bf(v0.y); a[2] = f2bf(v0.z); a[3] = f2bf(v0.w);
        a[4] = f2bf(v1.x); a[5] = f2bf(v1.y); a[6] = f2bf(v1.z); a[7] = f2bf(v1.w);
        *(bf16x8*)&ab[s * HBS + 32 * wv + q * 8] = a;
    }
    __syncthreads();

    // ---- in_proj GEMM: each wave 16 rows x 32 cols ----
    {
        bf16x8 af[4];
        #pragma unroll
        for (int ks = 0; ks < 4; ++ks)
            af[ks] = *(const bf16x8*)&ab[s * HBS + ks * 32 + q * 8];
        #pragma unroll
        for (int t = 0; t < 2; ++t) acc[t] = (f32x4){0.f, 0.f, 0.f, 0.f};
        #pragma unroll
        for (int ks = 0; ks < 4; ++ks) {
            #pragma unroll
            for (int t = 0; t < 2; ++t) {
                bf16x8 b = *(const bf16x8*)&wt[(32 * wv + 16 * t + s) * H + ks * 32 + q * 8];
                acc[t] = __builtin_amdgcn_mfma_f32_16x16x32_bf16(af[ks], b, acc[t], 0, 0, 0);
            }
        }
        __syncthreads();   // all x-tile reads complete before h overwrites ab
        #pragma unroll
        for (int t = 0; t < 2; ++t) {
            int n = 32 * wv + 16 * t + s;
            float bi = b_in[n];
            #pragma unroll
            for (int r = 0; r < 4; ++r) {
                h[t][r] = acc[t][r] + bi;
                ab[(4 * q + r) * HBS + n] = f2bf(h[t][r]);
            }
        }
        __syncthreads();
    }

    // degree-4 Chebyshev-truncated minimax of e^v on [-1,1]
    const float cm[KT] = {1.00004478f, 0.99730768f, 0.49919676f, 0.17734736f, 0.04379392f};

    #pragma unroll 1
    for (int layer = 0; layer < NATT; ++layer) {
        const ushort* WT = wt + (size_t)(1 + layer) * 16384;

        // ---- phase A: u = tanh(h @ W + b); A-frags from shared bf16 tile ----
        bf16x8 af[4];
        #pragma unroll
        for (int ks = 0; ks < 4; ++ks)
            af[ks] = *(const bf16x8*)&ab[s * HBS + ks * 32 + q * 8];
        #pragma unroll
        for (int t = 0; t < 2; ++t) acc[t] = (f32x4){0.f, 0.f, 0.f, 0.f};
        #pragma unroll
        for (int ks = 0; ks < 4; ++ks) {
            #pragma unroll
            for (int t = 0; t < 2; ++t) {
                bf16x8 b = *(const bf16x8*)&WT[(32 * wv + 16 * t + s) * H + ks * 32 + q * 8];
                acc[t] = __builtin_amdgcn_mfma_f32_16x16x32_bf16(af[ks], b, acc[t], 0, 0, 0);
            }
        }
        float u[2][4];
        #pragma unroll
        for (int t = 0; t < 2; ++t) {
            float ba = b_att[layer * H + 32 * wv + 16 * t + s];
            #pragma unroll
            for (int r = 0; r < 4; ++r) u[t][r] = fast_tanh(acc[t][r] + ba);
        }

        // ---- partial raw moments over this wave's 32 cols ----
        float S[4][KT], T[4][KT - 1];
        #pragma unroll
        for (int r = 0; r < 4; ++r) {
            #pragma unroll
            for (int k = 0; k < KT; ++k) S[r][k] = 0.f;
            #pragma unroll
            for (int k = 0; k < KT - 1; ++k) T[r][k] = 0.f;
        }
        #pragma unroll
        for (int t = 0; t < 2; ++t) {
            #pragma unroll
            for (int r = 0; r < 4; ++r) {
                float uu = u[t][r], hh = h[t][r];
                S[r][0] += hh;
                float p = uu;
                S[r][1] += p * hh; T[r][0] += p;
                #pragma unroll
                for (int k = 2; k < KT; ++k) {
                    p *= uu;
                    S[r][k] += p * hh;
                    T[r][k - 1] += p;
                }
            }
        }
        #pragma unroll
        for (int r = 0; r < 4; ++r) {
            #pragma unroll
            for (int k = 0; k < KT; ++k)     S[r][k] = red16(S[r][k]);
            #pragma unroll
            for (int k = 0; k < KT - 1; ++k) T[r][k] = red16(T[r][k]);
        }
        // cross-wave moment exchange: s==0 lane of each quad writes rows 4q..4q+3
        if (s == 0) {
            #pragma unroll
            for (int r = 0; r < 4; ++r) {
                float* dst = &exm[(wv * 16 + 4 * q + r) * 12];
                *(f32x4*)&dst[0] = (f32x4){S[r][0], S[r][1], S[r][2], S[r][3]};
                *(f32x4*)&dst[4] = (f32x4){S[r][4], T[r][0], T[r][1], T[r][2]};
                dst[8] = T[r][3];
            }
        }
        __syncthreads();
        // branch-free combine: red16 is an all-reduce, so our own LDS copy equals
        // our register copy — just sum all four waves' copies.
        #pragma unroll
        for (int r = 0; r < 4; ++r) {
            f32x4 s0 = (f32x4){0.f, 0.f, 0.f, 0.f};
            f32x4 s1 = (f32x4){0.f, 0.f, 0.f, 0.f};
            float s2 = 0.f;
            #pragma unroll
            for (int ow = 0; ow < 4; ++ow) {
                const float* src = &exm[(ow * 16 + 4 * q + r) * 12];
                s0 += *(const f32x4*)&src[0];
                s1 += *(const f32x4*)&src[4];
                s2 += src[8];
            }
            S[r][0] = s0.x * cm[0];
            S[r][1] = s0.y * cm[1];
            S[r][2] = s0.z * cm[2];
            S[r][3] = s0.w * cm[3];
            S[r][4] = s1.x * cm[4];
            T[r][0] = s1.y * cm[1];
            T[r][1] = s1.z * cm[2];
            T[r][2] = s1.w * cm[3];
            T[r][3] = s2   * cm[4];
        }

        // ---- Horner + residual + LN partials (own 32 cols) ----
        float ls[4] = {0, 0, 0, 0}, lq[4] = {0, 0, 0, 0};
        #pragma unroll
        for (int t = 0; t < 2; ++t) {
            #pragma unroll
            for (int r = 0; r < 4; ++r) {
                float uu = u[t][r];
                float num = S[r][KT - 1];
                #pragma unroll
                for (int k = KT - 2; k >= 0; --k) num = num * uu + S[r][k];
                float den = T[r][KT - 2];
                #pragma unroll
                for (int k = KT - 3; k >= 0; --k) den = den * uu + T[r][k];
                den = den * uu + 128.f * 1.00004478f;   // c0 * T0
                float yy = h[t][r] + num * __builtin_amdgcn_rcpf(den);
                h[t][r] = yy;
                ls[r] += yy; lq[r] += yy * yy;
            }
        }
        #pragma unroll
        for (int r = 0; r < 4; ++r) { ls[r] = red16(ls[r]); lq[r] = red16(lq[r]); }
        if (s == 0) {
            #pragma unroll
            for (int r = 0; r < 4; ++r)
                *(float2*)&exl[(wv * 16 + 4 * q + r) * 2] = make_float2(ls[r], lq[r]);
        }
        __syncthreads();
        float mu[4], inv[4];
        #pragma unroll
        for (int r = 0; r < 4; ++r) {
            float sm = 0.f, sq = 0.f;
            #pragma unroll
            for (int ow = 0; ow < 4; ++ow) {
                float2 o = *(const float2*)&exl[(ow * 16 + 4 * q + r) * 2];
                sm += o.x; sq += o.y;
            }
            mu[r] = sm * (1.f / H);
            float var = sq * (1.f / H) - mu[r] * mu[r];
            inv[r] = rsqrtf(var + EPS);
        }
        // ---- epilogue: h = (y-mu)*inv*gamma + beta ; refresh shared bf16 tile ----
        #pragma unroll
        for (int t = 0; t < 2; ++t) {
            int n = 32 * wv + 16 * t + s;
            float g  = gamma[layer * H + n];
            float be = beta [layer * H + n];
            #pragma unroll
            for (int r = 0; r < 4; ++r) {
                float hn = (h[t][r] - mu[r]) * inv[r] * g + be;
                h[t][r] = hn;
                ab[(4 * q + r) * HBS + n] = f2bf(hn);
            }
        }
        __syncthreads();
    }

    // ---- final proj: wave 0 computes 16 rows x NC via one MFMA tile ----
    if (wv == 0) {
        const ushort* WC = wt + 4 * 16384;
        f32x4 facc = (f32x4){0.f, 0.f, 0.f, 0.f};
        #pragma unroll
        for (int ks = 0; ks < 4; ++ks) {
            bf16x8 a = *(const bf16x8*)&ab[s * HBS + ks * 32 + q * 8];
            bf16x8 b = *(const bf16x8*)&WC[s * H + ks * 32 + q * 8];
            facc = __builtin_amdgcn_mfma_f32_16x16x32_bf16(a, b, facc, 0, 0, 0);
        }
        if (s < NC) {
            float bc = b_c[s];
            #pragma unroll
            for (int r = 0; r < 4; ++r)
                out[(rowBase + 4 * q + r) * NC + s] = facc[r] + bc;
        }
    }
}

extern "C" void kernel_launch(void* const* d_in, const int* in_sizes, int n_in,
                              void* d_out, int out_size, void* d_ws, size_t ws_size,
                              hipStream_t stream) {
    const float* x     = (const float*)d_in[0];
    const float* W_in  = (const float*)d_in[1];
    const float* b_in  = (const float*)d_in[2];
    const float* W_att = (const float*)d_in[3];
    const float* b_att = (const float*)d_in[4];
    const float* gamma = (const float*)d_in[5];
    const float* beta  = (const float*)d_in[6];
    const float* W_c   = (const float*)d_in[7];
    const float* b_c   = (const float*)d_in[8];
    float* out  = (float*)d_out;
    ushort* wt  = (ushort*)d_ws;    // 5 mats: 4*16384 + 2048 ushorts = 136 KiB

    hipLaunchKernelGGL(prep_weights, dim3(264), dim3(256), 0, stream,
                       W_in, W_att, W_c, wt);
    hipLaunchKernelGGL(simple_attention_kernel, dim3(B_TOT / TR), dim3(256), 0, stream,
                       x, b_in, b_att, gamma, beta, b_c, wt, out);
}